// Round 5
// baseline (3092.330 us; speedup 1.0000x reference)
//
#include <hip/hip_runtime.h>
#include <hip/hip_fp16.h>

// Problem constants
#define BB 16
#define TT 256
#define HH 512
#define EE 256
#define VV 32000

using half8   = __attribute__((ext_vector_type(8))) _Float16;
using float4v = __attribute__((ext_vector_type(4))) float;
typedef unsigned long long u64;

// ---------------- ws layout (bytes) ----------------
#define WS_WFC16   0u                       // 32000*512*2 = 32768000
#define WS_XG      32768000u                // 4096*256*2  = 2097152
#define WS_WIH0    34865152u                // 512*256*2   = 262144
#define WS_WIH1    35127296u                // 512*512*2   = 524288
#define WS_XP0     35651584u                // 256*16*512*4= 8388608  (t-major [T][B][H], incl b_ih0+b_hh0)
#define WS_XP1     44040192u                // 8388608  (t-major [T][B][H], incl b_ih1+b_hh1)
#define WS_H0EX    52428800u                // 4194304  [T][16][256] u32 (f16 pairs)
#define WS_H1EX    56623104u                // 4194304  [T][16][256] u32 (f16 pairs; FC GEMM reads via APERM)
#define WS_FLAGS   60817408u                // 12288 used (flags0 512, flags1 512, flagsS 2048 u32)
#define WS_NEEDED  60833792u

// ---------------- tiny prep kernels ----------------
__global__ void init_flags_k(unsigned* f) {
    f[blockIdx.x * 256 + threadIdx.x] = 0u;   // 12*256 = 3072 entries
}

__global__ void cvt_f32_f16_k(const float* __restrict__ s, _Float16* __restrict__ d, int n) {
    int i = blockIdx.x * 256 + threadIdx.x;
    if (i < n) d[i] = (_Float16)s[i];
}

__global__ void gather_embed_k(const int* __restrict__ X, const float* __restrict__ emb,
                               _Float16* __restrict__ xg) {
    int m = blockIdx.x;            // m = b*T + t
    int e = threadIdx.x;           // 256 threads
    int row = X[m];
    xg[m * EE + e] = (_Float16)emb[(size_t)row * EE + e];
}

// ---------------- generic f16 GEMM: C[M,N] = A[M,K] * B[N,K]^T + bias0 + bias1 ----------------
// PERM : store C at [t][b][n] with logical row m = b*256+t  (xp0 production)
// APERM: read A row m from physical row (m&255)*16 + (m>>8) (h1ex consumption: [t*16+b] rows)
template <bool PERM, bool APERM>
__global__ __launch_bounds__(256)
void gemm_f16_k(const _Float16* __restrict__ A, const _Float16* __restrict__ Bm,
                const float* __restrict__ bias0, const float* __restrict__ bias1,
                float* __restrict__ C, int M, int N, int K) {
    __shared__ _Float16 As[128][40];
    __shared__ _Float16 Bs[128][40];
    const int tid = threadIdx.x;
    const int l = tid & 63, w = tid >> 6;
    const int ntiles = N >> 7;
    const int m0 = (blockIdx.x / ntiles) << 7;
    const int n0 = (blockIdx.x % ntiles) << 7;
    const int wr = (w >> 1) << 6, wc = (w & 1) << 6;
    const int lrow = tid >> 1, lseg = (tid & 1) << 4;
    const int ar = l & 15, ak = (l >> 4) << 3;

    float4v acc[4][4] = {};

    const int am = m0 + lrow;
    const size_t arow = APERM ? (size_t)((am & 255) * 16 + (am >> 8)) : (size_t)am;

    for (int kt = 0; kt < K; kt += 32) {
        const _Float16* ga = A  + arow * K + kt + lseg;
        const _Float16* gb = Bm + (size_t)(n0 + lrow) * K + kt + lseg;
        *(int4*)&As[lrow][lseg]     = *(const int4*)ga;
        *(int4*)&As[lrow][lseg + 8] = *(const int4*)(ga + 8);
        *(int4*)&Bs[lrow][lseg]     = *(const int4*)gb;
        *(int4*)&Bs[lrow][lseg + 8] = *(const int4*)(gb + 8);
        __syncthreads();

        half8 af[4], bf[4];
#pragma unroll
        for (int m = 0; m < 4; ++m) af[m] = *(half8*)&As[wr + m * 16 + ar][ak];
#pragma unroll
        for (int n = 0; n < 4; ++n) bf[n] = *(half8*)&Bs[wc + n * 16 + ar][ak];
#pragma unroll
        for (int m = 0; m < 4; ++m)
#pragma unroll
            for (int n = 0; n < 4; ++n)
                acc[m][n] = __builtin_amdgcn_mfma_f32_16x16x32_f16(af[m], bf[n], acc[m][n], 0, 0, 0);
        __syncthreads();
    }

#pragma unroll
    for (int m = 0; m < 4; ++m) {
#pragma unroll
        for (int n = 0; n < 4; ++n) {
            const int col = n0 + wc + n * 16 + (l & 15);
            float bv = (bias0 ? bias0[col] : 0.f) + (bias1 ? bias1[col] : 0.f);
#pragma unroll
            for (int r = 0; r < 4; ++r) {
                const int row = m0 + wr + m * 16 + ((l >> 4) << 2) + r;
                float v = acc[m][n][r] + bv;
                if (PERM) {
                    int t = row & 255, b = row >> 8;
                    C[(size_t)((t << 4) + b) * HH + col] = v;
                } else {
                    C[(size_t)row * N + col] = v;
                }
            }
        }
    }
}

// fast tanh: 1 - 2/(e^{2x}+1)
__device__ __forceinline__ float tanh_fast(float x) {
    float e = __expf(2.0f * x);
    return 1.0f - 2.0f * __builtin_amdgcn_rcpf(e + 1.0f);
}

// ---------------- fused RNN pipeline (flag protocol, reduced parties) ----------------
// grid = 68 blocks x 256 threads (4 waves).
//   blocks 0..3: recurrence. block = (layer<<1)|p: cols [p*256, p*256+256), 4 waves x 64 cols.
//     W_hh fragments wf[4][16] fully in VGPRs (256/wave; launch_bounds(256,1) -> 512 budget).
//     hbuf holds FULL 512-col h[t-1]: local cols written at tail; remote half staged from
//     exchange (u64 relaxed agent loads) after the partner's flag for t-1 is acquired.
//     Deferred flag: at top of step t, vmcnt(0)+barrier (all waves' t-1 publishes drained),
//     then one release flag — producer-side drain cost hidden under the step.
//   blocks 4..67: xp1 stage (cs in 0..7 [64 cols], j in 0..7 [t-stripe]):
//     poll flags0[t] (both layer-0 blocks), read h0ex directly as A-fragments,
//     xp1[t] = h0[t]@W_ih1^T + b_ih1 + b_hh1, publish, __syncthreads (drain), flag.
__global__ __launch_bounds__(256, 1)
void rnn_pipe_k(const float* __restrict__ Whh0, const float* __restrict__ Whh1,
                const _Float16* __restrict__ Wih1f16,
                const float* __restrict__ bih1, const float* __restrict__ bhh1,
                const float* __restrict__ xp0, float* __restrict__ xp1,
                unsigned* __restrict__ h0ex, unsigned* __restrict__ h1ex,
                float* __restrict__ out_hidden, float* __restrict__ out2f32,
                unsigned* __restrict__ flags0, unsigned* __restrict__ flags1,
                unsigned* __restrict__ flagsS)
{
    __shared__ _Float16 hbuf[16][520];   // full-width h[t-1]; 16.6 KB

    const int tid = threadIdx.x;
    const int l = tid & 63, w = tid >> 6;     // 4 waves
    const int lq = l >> 4;                    // 0..3
    const int kq = lq << 3;                   // {0,8,16,24}
    const int c15 = l & 15;
    const int bi = blockIdx.x;

    if (bi < 4) {
        // ================= recurrence =================
        const int layer = bi >> 1, p = bi & 1;
        const float* Whh = layer ? Whh1 : Whh0;
        const int rk = (1 - p) * 256;                     // remote col/k base
        unsigned* myfl = layer ? flags1 : flags0;
        unsigned* pfl  = myfl;                            // partner flags, same array
        unsigned* hex  = layer ? h1ex : h0ex;             // own publish buffer
        const u64* rex = (const u64*)hex;                 // remote reads, same buffer

        int col[4];
#pragma unroll
        for (int ct = 0; ct < 4; ++ct) col[ct] = p * 256 + w * 64 + ct * 16 + c15;

        // --- W_hh fragments: wf[4][16] = 256 VGPRs ---
        half8 wf[4][16];
#pragma unroll
        for (int ct = 0; ct < 4; ++ct) {
            const float* wrow = Whh + (size_t)col[ct] * HH;
#pragma unroll
            for (int kt = 0; kt < 16; ++kt) {
                const float* s = wrow + kt * 32 + kq;
                float4v f0 = *(const float4v*)s;
                float4v f1 = *(const float4v*)(s + 4);
                half8 h;
#pragma unroll
                for (int i = 0; i < 4; ++i) { h[i] = (_Float16)f0[i]; h[i + 4] = (_Float16)f1[i]; }
                wf[ct][kt] = h;
            }
        }

        for (int t = 0; t < TT; ++t) {
            // ---- A: deferred flag for t-1 (all waves drain, then one release) ----
            if (t > 0) {
                asm volatile("s_waitcnt vmcnt(0)" ::: "memory");
                asm volatile("" ::: "memory");
                __builtin_amdgcn_s_barrier();
                asm volatile("" ::: "memory");
                if (tid == 0)
                    __hip_atomic_store(&myfl[(t - 1) * 2 + p], 1u,
                                       __ATOMIC_RELEASE, __HIP_MEMORY_SCOPE_AGENT);
            }

            // ---- B: wave0 polls producers ----
            if (w == 0) {
                for (;;) {
                    unsigned v = 1u;
                    if (layer == 0) {
                        if (t > 0 && l == 0)
                            v = __hip_atomic_load(&pfl[(t - 1) * 2 + (1 - p)],
                                                  __ATOMIC_ACQUIRE, __HIP_MEMORY_SCOPE_AGENT);
                    } else {
                        if (t > 0 && l == 0)
                            v = __hip_atomic_load(&pfl[(t - 1) * 2 + (1 - p)],
                                                  __ATOMIC_ACQUIRE, __HIP_MEMORY_SCOPE_AGENT);
                        else if (l >= 4 && l < 8)
                            v = __hip_atomic_load(&flagsS[t * 8 + p * 4 + (l - 4)],
                                                  __ATOMIC_ACQUIRE, __HIP_MEMORY_SCOPE_AGENT);
                    }
                    if (__all(v != 0)) break;
                    __builtin_amdgcn_s_sleep(4);
                }
            }
            __syncthreads();

            // ---- C: stage remote half of h[t-1] into hbuf; load acc = xp[t] ----
            if (t > 0) {
#pragma unroll
                for (int j = 0; j < 4; ++j) {
                    int idx = j * 256 + tid;          // 0..1023
                    int b = idx >> 6, q = idx & 63;   // q: u64 within remote half-row
                    u64 d = __hip_atomic_load(rex + ((size_t)(t - 1) * 16 + b) * 128 + (rk >> 2) + q,
                                              __ATOMIC_RELAXED, __HIP_MEMORY_SCOPE_AGENT);
                    *(u64*)&hbuf[b][rk + q * 4] = d;
                }
            }
            float4v acc[4];
#pragma unroll
            for (int ct = 0; ct < 4; ++ct) {
#pragma unroll
                for (int r = 0; r < 4; ++r) {
                    if (layer == 0)
                        acc[ct][r] = xp0[(size_t)(t * 16 + lq * 4 + r) * HH + col[ct]];
                    else
                        acc[ct][r] = __hip_atomic_load(&xp1[(size_t)(t * 16 + lq * 4 + r) * HH + col[ct]],
                                                       __ATOMIC_RELAXED, __HIP_MEMORY_SCOPE_AGENT);
                }
            }

            // ---- D: hbuf complete (remote staged here + local written at prev tail) ----
            if (t > 0) {
                asm volatile("s_waitcnt lgkmcnt(0)" ::: "memory");
                __builtin_amdgcn_s_barrier();
                asm volatile("" ::: "memory");

                // ---- E: MFMA over full K ----
#pragma unroll
                for (int kt = 0; kt < 16; ++kt) {
                    half8 a = *(const half8*)&hbuf[c15][kt * 32 + kq];
                    acc[0] = __builtin_amdgcn_mfma_f32_16x16x32_f16(a, wf[0][kt], acc[0], 0, 0, 0);
                    acc[1] = __builtin_amdgcn_mfma_f32_16x16x32_f16(a, wf[1][kt], acc[1], 0, 0, 0);
                    acc[2] = __builtin_amdgcn_mfma_f32_16x16x32_f16(a, wf[2][kt], acc[2], 0, 0, 0);
                    acc[3] = __builtin_amdgcn_mfma_f32_16x16x32_f16(a, wf[3][kt], acc[3], 0, 0, 0);
                }
            }

            // ---- F: tanh + outputs + pack ----
            unsigned pk[4][4];
#pragma unroll
            for (int ct = 0; ct < 4; ++ct) {
#pragma unroll
                for (int r = 0; r < 4; ++r) {
                    const int b = lq * 4 + r;
                    float hv = tanh_fast(acc[ct][r]);
                    if (layer == 1)
                        out2f32[((size_t)(b << 8) + t) * HH + col[ct]] = hv;
                    if (t == TT - 1)
                        out_hidden[(size_t)(layer * BB + b) * HH + col[ct]] = hv;
                    unsigned short mu = __builtin_bit_cast(unsigned short, (_Float16)hv);
                    int ov = __shfl_xor((int)mu, 1, 64);
                    pk[ct][r] = (unsigned)mu | ((unsigned)ov << 16);   // valid on even lanes
                }
            }

            // ---- G: publish own cols (relaxed agent stores; drained at next A) ----
            if ((l & 1) == 0) {
#pragma unroll
                for (int ct = 0; ct < 4; ++ct) {
#pragma unroll
                    for (int r = 0; r < 4; ++r) {
                        const int b = lq * 4 + r;
                        __hip_atomic_store(&hex[((size_t)t * 16 + b) * 256 + (col[ct] >> 1)], pk[ct][r],
                                           __ATOMIC_RELAXED, __HIP_MEMORY_SCOPE_AGENT);
                    }
                }
            }

            // ---- H: tail — all waves done reading hbuf; write local h[t] cols ----
            asm volatile("" ::: "memory");
            __builtin_amdgcn_s_barrier();
            asm volatile("" ::: "memory");
            if ((l & 1) == 0) {
#pragma unroll
                for (int ct = 0; ct < 4; ++ct) {
#pragma unroll
                    for (int r = 0; r < 4; ++r)
                        *(unsigned*)&hbuf[lq * 4 + r][col[ct]] = pk[ct][r];
                }
            }
            // next iteration's D (lgkmcnt+barrier) makes these visible before reads
        }

        // final flag for t = TT-1 (stage blocks need layer-0's; layer-1's harmless)
        asm volatile("s_waitcnt vmcnt(0)" ::: "memory");
        asm volatile("" ::: "memory");
        __builtin_amdgcn_s_barrier();
        asm volatile("" ::: "memory");
        if (tid == 0)
            __hip_atomic_store(&myfl[(TT - 1) * 2 + p], 1u,
                               __ATOMIC_RELEASE, __HIP_MEMORY_SCOPE_AGENT);
    } else {
        // ================= xp1 stage =================
        const int sb = bi - 4;
        const int cs = sb & 7;          // 64-col slice
        const int j  = sb >> 3;         // t-stripe 0..7
        const int col = cs * 64 + w * 16 + c15;

        half8 wfi[16];
#pragma unroll
        for (int kt = 0; kt < 16; ++kt)
            wfi[kt] = *(const half8*)(Wih1f16 + (size_t)col * HH + kt * 32 + kq);
        const float bsum = bih1[col] + bhh1[col];

        const u64* hx = (const u64*)h0ex;

        for (int t = j; t < TT; t += 8) {
            // poll both layer-0 block flags for step t
            if (w == 0) {
                for (;;) {
                    unsigned v = 1u;
                    if (l < 2)
                        v = __hip_atomic_load(&flags0[t * 2 + l],
                                              __ATOMIC_ACQUIRE, __HIP_MEMORY_SCOPE_AGENT);
                    if (__all(v != 0)) break;
                    __builtin_amdgcn_s_sleep(16);
                }
            }
            __syncthreads();

            // h0[t] A-fragments direct from exchange (relaxed agent u64 loads)
            half8 af[16];
            const size_t rb = ((size_t)t * 16 + c15) * 128 + (kq >> 2);
#pragma unroll
            for (int kt = 0; kt < 16; ++kt) {
                u64 d0 = __hip_atomic_load(hx + rb + kt * 8,     __ATOMIC_RELAXED, __HIP_MEMORY_SCOPE_AGENT);
                u64 d1 = __hip_atomic_load(hx + rb + kt * 8 + 1, __ATOMIC_RELAXED, __HIP_MEMORY_SCOPE_AGENT);
                union { u64 u[2]; half8 h; } cv;
                cv.u[0] = d0; cv.u[1] = d1;
                af[kt] = cv.h;
            }
            float4v acc = {bsum, bsum, bsum, bsum};
#pragma unroll
            for (int kt = 0; kt < 16; ++kt)
                acc = __builtin_amdgcn_mfma_f32_16x16x32_f16(af[kt], wfi[kt], acc, 0, 0, 0);

            // publish xp1[t] then flag (syncthreads drains stores first)
#pragma unroll
            for (int r = 0; r < 4; ++r)
                __hip_atomic_store(&xp1[(size_t)(t * 16 + lq * 4 + r) * HH + col], acc[r],
                                   __ATOMIC_RELAXED, __HIP_MEMORY_SCOPE_AGENT);
            __syncthreads();   // implicit vmcnt(0) per wave before barrier
            if (tid == 0)
                __hip_atomic_store(&flagsS[t * 8 + cs], 1u,
                                   __ATOMIC_RELEASE, __HIP_MEMORY_SCOPE_AGENT);
        }
    }
}

// ---------------- launch ----------------
extern "C" void kernel_launch(void* const* d_in, const int* in_sizes, int n_in,
                              void* d_out, int out_size, void* d_ws, size_t ws_size,
                              hipStream_t stream) {
    if (ws_size < WS_NEEDED) return;  // loud failure rather than corruption

    const int*   X     = (const int*)d_in[0];
    const float* emb   = (const float*)d_in[1];
    const float* Wih0  = (const float*)d_in[2];
    const float* Whh0  = (const float*)d_in[3];
    const float* bih0  = (const float*)d_in[4];
    const float* bhh0  = (const float*)d_in[5];
    const float* Wih1  = (const float*)d_in[6];
    const float* Whh1  = (const float*)d_in[7];
    const float* bih1  = (const float*)d_in[8];
    const float* bhh1  = (const float*)d_in[9];
    const float* Wfc   = (const float*)d_in[10];
    const float* bfc   = (const float*)d_in[11];

    char* ws = (char*)d_ws;
    _Float16* Wfc16   = (_Float16*)(ws + WS_WFC16);
    _Float16* xg      = (_Float16*)(ws + WS_XG);
    _Float16* Wih0f16 = (_Float16*)(ws + WS_WIH0);
    _Float16* Wih1f16 = (_Float16*)(ws + WS_WIH1);
    float*    xp0     = (float*)(ws + WS_XP0);
    float*    xp1     = (float*)(ws + WS_XP1);
    unsigned* h0ex    = (unsigned*)(ws + WS_H0EX);
    unsigned* h1ex    = (unsigned*)(ws + WS_H1EX);
    unsigned* flags0  = (unsigned*)(ws + WS_FLAGS);
    unsigned* flags1  = flags0 + 512;
    unsigned* flagsS  = flags0 + 1024;

    float* logits     = (float*)d_out;                          // [16,256,32000]
    float* hidden     = (float*)d_out + (size_t)BB * TT * VV;   // [2,16,512]
    float* out2       = hidden + 2 * BB * HH;                   // [16,256,512]

    // prep
    hipLaunchKernelGGL(init_flags_k, dim3(12), dim3(256), 0, stream, flags0);
    hipLaunchKernelGGL(gather_embed_k, dim3(BB * TT), dim3(256), 0, stream, X, emb, xg);
    hipLaunchKernelGGL(cvt_f32_f16_k, dim3((HH * EE) / 256), dim3(256), 0, stream, Wih0, Wih0f16, HH * EE);
    hipLaunchKernelGGL(cvt_f32_f16_k, dim3((HH * HH) / 256), dim3(256), 0, stream, Wih1, Wih1f16, HH * HH);
    hipLaunchKernelGGL(cvt_f32_f16_k, dim3((VV * HH) / 256), dim3(256), 0, stream, Wfc, Wfc16, VV * HH);

    // layer-0 input projection -> xp0 (t-major), bias = b_ih0 + b_hh0
    hipLaunchKernelGGL((gemm_f16_k<true, false>), dim3((4096 / 128) * (HH / 128)), dim3(256), 0, stream,
                       xg, Wih0f16, bih0, bhh0, xp0, 4096, HH, EE);

    // fused flag-protocol recurrence (4 rec blocks + 64 xp1-stage blocks)
    hipLaunchKernelGGL(rnn_pipe_k, dim3(68), dim3(256), 0, stream,
                       Whh0, Whh1, Wih1f16, bih1, bhh1, xp0, xp1,
                       h0ex, h1ex, hidden, out2, flags0, flags1, flagsS);

    // final FC: logits = h1ex(APERM rows t*16+b) @ Wfc^T + b_fc
    hipLaunchKernelGGL((gemm_f16_k<false, true>), dim3((4096 / 128) * (VV / 128)), dim3(256), 0, stream,
                       (const _Float16*)h1ex, Wfc16, bfc, nullptr, logits, 4096, VV, HH);
}

// Round 7
// 2621.202 us; speedup vs baseline: 1.1797x; 1.1797x over previous
//
#include <hip/hip_runtime.h>
#include <hip/hip_fp16.h>

// Problem constants
#define BB 16
#define TT 256
#define HH 512
#define EE 256
#define VV 32000

using half8   = __attribute__((ext_vector_type(8))) _Float16;
using float4v = __attribute__((ext_vector_type(4))) float;
typedef unsigned long long u64;

// ---------------- ws layout (bytes) ----------------
#define WS_WFC16   0u                       // 32000*512*2 = 32768000
#define WS_XG      32768000u                // 4096*256*2  = 2097152
#define WS_WIH0    34865152u                // 512*256*2   = 262144
#define WS_WIH1    35127296u                // 512*512*2   = 524288
#define WS_XP0     35651584u                // 256*16*512*4= 8388608  (t-major [T][B][H], incl b_ih0+b_hh0)
#define WS_XP1     44040192u                // 8388608  (t-major [T][B][H], incl b_ih1+b_hh1)
#define WS_H0EX    52428800u                // 4194304  [T][16][256] u32 (f16 pairs)
#define WS_H1EX    56623104u                // 4194304  [T][16][256] u32 (f16 pairs; FC GEMM reads via APERM)
#define WS_FLAGS   60817408u                // 16384: flags0 1024 u32, flags1 1024 u32, flagsS 2048 u32
#define WS_NEEDED  60833792u

// ---------------- tiny prep kernels ----------------
__global__ void init_flags_k(unsigned* f) {
    f[blockIdx.x * 256 + threadIdx.x] = 0u;   // 16*256 = 4096 entries
}

__global__ void cvt_f32_f16_k(const float* __restrict__ s, _Float16* __restrict__ d, int n) {
    int i = blockIdx.x * 256 + threadIdx.x;
    if (i < n) d[i] = (_Float16)s[i];
}

__global__ void gather_embed_k(const int* __restrict__ X, const float* __restrict__ emb,
                               _Float16* __restrict__ xg) {
    int m = blockIdx.x;            // m = b*T + t
    int e = threadIdx.x;           // 256 threads
    int row = X[m];
    xg[m * EE + e] = (_Float16)emb[(size_t)row * EE + e];
}

// ---------------- generic f16 GEMM: C[M,N] = A[M,K] * B[N,K]^T + bias0 + bias1 ----------------
// PERM : store C at [t][b][n] with logical row m = b*256+t  (xp0 production)
// APERM: read A row m from physical row (m&255)*16 + (m>>8) (h1ex consumption: [t*16+b] rows)
template <bool PERM, bool APERM>
__global__ __launch_bounds__(256)
void gemm_f16_k(const _Float16* __restrict__ A, const _Float16* __restrict__ Bm,
                const float* __restrict__ bias0, const float* __restrict__ bias1,
                float* __restrict__ C, int M, int N, int K) {
    __shared__ _Float16 As[128][40];
    __shared__ _Float16 Bs[128][40];
    const int tid = threadIdx.x;
    const int l = tid & 63, w = tid >> 6;
    const int ntiles = N >> 7;
    const int m0 = (blockIdx.x / ntiles) << 7;
    const int n0 = (blockIdx.x % ntiles) << 7;
    const int wr = (w >> 1) << 6, wc = (w & 1) << 6;
    const int lrow = tid >> 1, lseg = (tid & 1) << 4;
    const int ar = l & 15, ak = (l >> 4) << 3;

    float4v acc[4][4] = {};

    const int am = m0 + lrow;
    const size_t arow = APERM ? (size_t)((am & 255) * 16 + (am >> 8)) : (size_t)am;

    for (int kt = 0; kt < K; kt += 32) {
        const _Float16* ga = A  + arow * K + kt + lseg;
        const _Float16* gb = Bm + (size_t)(n0 + lrow) * K + kt + lseg;
        *(int4*)&As[lrow][lseg]     = *(const int4*)ga;
        *(int4*)&As[lrow][lseg + 8] = *(const int4*)(ga + 8);
        *(int4*)&Bs[lrow][lseg]     = *(const int4*)gb;
        *(int4*)&Bs[lrow][lseg + 8] = *(const int4*)(gb + 8);
        __syncthreads();

        half8 af[4], bf[4];
#pragma unroll
        for (int m = 0; m < 4; ++m) af[m] = *(half8*)&As[wr + m * 16 + ar][ak];
#pragma unroll
        for (int n = 0; n < 4; ++n) bf[n] = *(half8*)&Bs[wc + n * 16 + ar][ak];
#pragma unroll
        for (int m = 0; m < 4; ++m)
#pragma unroll
            for (int n = 0; n < 4; ++n)
                acc[m][n] = __builtin_amdgcn_mfma_f32_16x16x32_f16(af[m], bf[n], acc[m][n], 0, 0, 0);
        __syncthreads();
    }

#pragma unroll
    for (int m = 0; m < 4; ++m) {
#pragma unroll
        for (int n = 0; n < 4; ++n) {
            const int col = n0 + wc + n * 16 + (l & 15);
            float bv = (bias0 ? bias0[col] : 0.f) + (bias1 ? bias1[col] : 0.f);
#pragma unroll
            for (int r = 0; r < 4; ++r) {
                const int row = m0 + wr + m * 16 + ((l >> 4) << 2) + r;
                float v = acc[m][n][r] + bv;
                if (PERM) {
                    int t = row & 255, b = row >> 8;
                    C[(size_t)((t << 4) + b) * HH + col] = v;
                } else {
                    C[(size_t)row * N + col] = v;
                }
            }
        }
    }
}

// fast tanh: 1 - 2/(e^{2x}+1)
__device__ __forceinline__ float tanh_fast(float x) {
    float e = __expf(2.0f * x);
    return 1.0f - 2.0f * __builtin_amdgcn_rcpf(e + 1.0f);
}

// ---------------- fused RNN pipeline (flag protocol, 4 partitions/layer) ----------------
// grid = 72 blocks x 256 threads (4 waves).
//   blocks 0..7: recurrence. block = layer*4 + p: cols [p*128, p*128+128), 4 waves x 32 cols.
//     W_hh fragments wf[2][16] = 128 VGPRs/wave — fits the 256 arch-VGPR cap cleanly with
//     transients (~220 total): NO spill, no AGPR juggling, builtins only (round-6 lesson:
//     inline-asm MFMA forfeits compiler hazard nops -> wrong results).
//     hbuf holds FULL 512-col h[t-1]: local quarter written at tail; 3 remote quarters staged
//     from exchange (u64 relaxed agent loads) after partner flags for t-1 acquired.
//     Deferred flag: at top of step t, vmcnt(0)+barrier, then one release flag.
//   blocks 8..71: xp1 stage (cs in 0..7 [64 cols], j in 0..7 [t-stripe]):
//     poll all 4 layer-0 flags for t, read h0ex directly as A-fragments,
//     xp1[t] = h0[t]@W_ih1^T + b_ih1 + b_hh1, publish, __syncthreads (drain), flag.
__global__ __launch_bounds__(256, 1)
void rnn_pipe_k(const float* __restrict__ Whh0, const float* __restrict__ Whh1,
                const _Float16* __restrict__ Wih1f16,
                const float* __restrict__ bih1, const float* __restrict__ bhh1,
                const float* __restrict__ xp0, float* __restrict__ xp1,
                unsigned* __restrict__ h0ex, unsigned* __restrict__ h1ex,
                float* __restrict__ out_hidden, float* __restrict__ out2f32,
                unsigned* __restrict__ flags0, unsigned* __restrict__ flags1,
                unsigned* __restrict__ flagsS)
{
    __shared__ _Float16 hbuf[16][520];   // full-width h[t-1]; 16.6 KB

    const int tid = threadIdx.x;
    const int l = tid & 63, w = tid >> 6;     // 4 waves
    const int lq = l >> 4;                    // 0..3
    const int kq = lq << 3;                   // {0,8,16,24}
    const int c15 = l & 15;
    const int bi = blockIdx.x;

    if (bi < 8) {
        // ================= recurrence =================
        const int layer = bi >> 2, p = bi & 3;
        const float* Whh = layer ? Whh1 : Whh0;
        unsigned* myfl = layer ? flags1 : flags0;
        unsigned* hex  = layer ? h1ex : h0ex;             // own publish buffer
        const u64* rex = (const u64*)hex;                 // remote reads, same buffer

        int col[2];
#pragma unroll
        for (int ct = 0; ct < 2; ++ct) col[ct] = p * 128 + w * 32 + ct * 16 + c15;

        // --- W_hh fragments: wf[2][16] = 128 VGPRs, plain builtin path ---
        half8 wf[2][16];
#pragma unroll
        for (int ct = 0; ct < 2; ++ct) {
            const float* wrow = Whh + (size_t)col[ct] * HH;
#pragma unroll
            for (int kt = 0; kt < 16; ++kt) {
                const float* s = wrow + kt * 32 + kq;
                float4v f0 = *(const float4v*)s;
                float4v f1 = *(const float4v*)(s + 4);
                half8 h;
#pragma unroll
                for (int i = 0; i < 4; ++i) { h[i] = (_Float16)f0[i]; h[i + 4] = (_Float16)f1[i]; }
                wf[ct][kt] = h;
            }
        }

        for (int t = 0; t < TT; ++t) {
            // ---- A: deferred flag for t-1 (all waves drain, then one release) ----
            if (t > 0) {
                asm volatile("s_waitcnt vmcnt(0)" ::: "memory");
                asm volatile("" ::: "memory");
                __builtin_amdgcn_s_barrier();
                asm volatile("" ::: "memory");
                if (tid == 0)
                    __hip_atomic_store(&myfl[(t - 1) * 4 + p], 1u,
                                       __ATOMIC_RELEASE, __HIP_MEMORY_SCOPE_AGENT);
            }

            // ---- B: wave0 polls producers ----
            if (w == 0) {
                for (;;) {
                    unsigned v = 1u;
                    if (t > 0 && l < 4)
                        v = __hip_atomic_load(&myfl[(t - 1) * 4 + l],
                                              __ATOMIC_ACQUIRE, __HIP_MEMORY_SCOPE_AGENT);
                    else if (layer == 1 && l >= 4 && l < 6)
                        v = __hip_atomic_load(&flagsS[t * 8 + p * 2 + (l - 4)],
                                              __ATOMIC_ACQUIRE, __HIP_MEMORY_SCOPE_AGENT);
                    if (__all(v != 0)) break;
                    __builtin_amdgcn_s_sleep(4);
                }
            }
            __syncthreads();

            // ---- C: stage 3 remote quarters of h[t-1] into hbuf; load acc = xp[t] ----
            if (t > 0) {
#pragma unroll
                for (int j = 0; j < 6; ++j) {
                    int idx = j * 256 + tid;            // 0..1535
                    int b = idx / 96, qq = idx % 96;    // 96 u64 of remote data per row
                    int q3 = qq >> 5, qo = qq & 31;     // quarter-of-three, u64 within quarter
                    int aq = q3 + (q3 >= p ? 1 : 0);    // skip own quarter
                    u64 d = __hip_atomic_load(rex + ((size_t)(t - 1) * 16 + b) * 128 + aq * 32 + qo,
                                              __ATOMIC_RELAXED, __HIP_MEMORY_SCOPE_AGENT);
                    *(u64*)&hbuf[b][aq * 128 + qo * 4] = d;
                }
            }
            float4v acc[2];
#pragma unroll
            for (int ct = 0; ct < 2; ++ct) {
#pragma unroll
                for (int r = 0; r < 4; ++r) {
                    if (layer == 0)
                        acc[ct][r] = xp0[(size_t)(t * 16 + lq * 4 + r) * HH + col[ct]];
                    else
                        acc[ct][r] = __hip_atomic_load(&xp1[(size_t)(t * 16 + lq * 4 + r) * HH + col[ct]],
                                                       __ATOMIC_RELAXED, __HIP_MEMORY_SCOPE_AGENT);
                }
            }

            // ---- D: hbuf complete (remote staged here + local written at prev tail) ----
            if (t > 0) {
                asm volatile("s_waitcnt lgkmcnt(0)" ::: "memory");
                __builtin_amdgcn_s_barrier();
                asm volatile("" ::: "memory");

                // ---- E: MFMA over full K (builtins; compiler handles MFMA hazards) ----
#pragma unroll
                for (int kt = 0; kt < 16; ++kt) {
                    half8 a = *(const half8*)&hbuf[c15][kt * 32 + kq];
                    acc[0] = __builtin_amdgcn_mfma_f32_16x16x32_f16(a, wf[0][kt], acc[0], 0, 0, 0);
                    acc[1] = __builtin_amdgcn_mfma_f32_16x16x32_f16(a, wf[1][kt], acc[1], 0, 0, 0);
                }
            }

            // ---- F: tanh + outputs + pack ----
            unsigned pk[2][4];
#pragma unroll
            for (int ct = 0; ct < 2; ++ct) {
#pragma unroll
                for (int r = 0; r < 4; ++r) {
                    const int b = lq * 4 + r;
                    float hv = tanh_fast(acc[ct][r]);
                    if (layer == 1)
                        out2f32[((size_t)(b << 8) + t) * HH + col[ct]] = hv;
                    if (t == TT - 1)
                        out_hidden[(size_t)(layer * BB + b) * HH + col[ct]] = hv;
                    unsigned short mu = __builtin_bit_cast(unsigned short, (_Float16)hv);
                    int ov = __shfl_xor((int)mu, 1, 64);
                    pk[ct][r] = (unsigned)mu | ((unsigned)ov << 16);   // valid on even lanes
                }
            }

            // ---- G: publish own cols (relaxed agent stores; drained at next A) ----
            if ((l & 1) == 0) {
#pragma unroll
                for (int ct = 0; ct < 2; ++ct) {
#pragma unroll
                    for (int r = 0; r < 4; ++r) {
                        const int b = lq * 4 + r;
                        __hip_atomic_store(&hex[((size_t)t * 16 + b) * 256 + (col[ct] >> 1)], pk[ct][r],
                                           __ATOMIC_RELAXED, __HIP_MEMORY_SCOPE_AGENT);
                    }
                }
            }

            // ---- H: tail — all waves done reading hbuf; write local h[t] cols ----
            asm volatile("" ::: "memory");
            __builtin_amdgcn_s_barrier();
            asm volatile("" ::: "memory");
            if ((l & 1) == 0) {
#pragma unroll
                for (int ct = 0; ct < 2; ++ct) {
#pragma unroll
                    for (int r = 0; r < 4; ++r)
                        *(unsigned*)&hbuf[lq * 4 + r][col[ct]] = pk[ct][r];
                }
            }
            // next iteration's D (lgkmcnt+barrier) makes these visible before reads
        }

        // final flag for t = TT-1 (stage blocks need layer-0's; layer-1's harmless)
        asm volatile("s_waitcnt vmcnt(0)" ::: "memory");
        asm volatile("" ::: "memory");
        __builtin_amdgcn_s_barrier();
        asm volatile("" ::: "memory");
        if (tid == 0)
            __hip_atomic_store(&myfl[(TT - 1) * 4 + p], 1u,
                               __ATOMIC_RELEASE, __HIP_MEMORY_SCOPE_AGENT);
    } else {
        // ================= xp1 stage =================
        const int sb = bi - 8;
        const int cs = sb & 7;          // 64-col slice
        const int j  = sb >> 3;         // t-stripe 0..7
        const int col = cs * 64 + w * 16 + c15;

        half8 wfi[16];
#pragma unroll
        for (int kt = 0; kt < 16; ++kt)
            wfi[kt] = *(const half8*)(Wih1f16 + (size_t)col * HH + kt * 32 + kq);
        const float bsum = bih1[col] + bhh1[col];

        const u64* hx = (const u64*)h0ex;

        for (int t = j; t < TT; t += 8) {
            // poll all 4 layer-0 block flags for step t
            if (w == 0) {
                for (;;) {
                    unsigned v = 1u;
                    if (l < 4)
                        v = __hip_atomic_load(&flags0[t * 4 + l],
                                              __ATOMIC_ACQUIRE, __HIP_MEMORY_SCOPE_AGENT);
                    if (__all(v != 0)) break;
                    __builtin_amdgcn_s_sleep(4);
                }
            }
            __syncthreads();

            // h0[t] A-fragments direct from exchange (relaxed agent u64 loads)
            half8 af[16];
            const size_t rb = ((size_t)t * 16 + c15) * 128 + (kq >> 2);
#pragma unroll
            for (int kt = 0; kt < 16; ++kt) {
                u64 d0 = __hip_atomic_load(hx + rb + kt * 8,     __ATOMIC_RELAXED, __HIP_MEMORY_SCOPE_AGENT);
                u64 d1 = __hip_atomic_load(hx + rb + kt * 8 + 1, __ATOMIC_RELAXED, __HIP_MEMORY_SCOPE_AGENT);
                union { u64 u[2]; half8 h; } cv;
                cv.u[0] = d0; cv.u[1] = d1;
                af[kt] = cv.h;
            }
            float4v acc = {bsum, bsum, bsum, bsum};
#pragma unroll
            for (int kt = 0; kt < 16; ++kt)
                acc = __builtin_amdgcn_mfma_f32_16x16x32_f16(af[kt], wfi[kt], acc, 0, 0, 0);

            // publish xp1[t] then flag (syncthreads drains stores first)
#pragma unroll
            for (int r = 0; r < 4; ++r)
                __hip_atomic_store(&xp1[(size_t)(t * 16 + lq * 4 + r) * HH + col], acc[r],
                                   __ATOMIC_RELAXED, __HIP_MEMORY_SCOPE_AGENT);
            __syncthreads();   // implicit vmcnt(0) per wave before barrier
            if (tid == 0)
                __hip_atomic_store(&flagsS[t * 8 + cs], 1u,
                                   __ATOMIC_RELEASE, __HIP_MEMORY_SCOPE_AGENT);
        }
    }
}

// ---------------- launch ----------------
extern "C" void kernel_launch(void* const* d_in, const int* in_sizes, int n_in,
                              void* d_out, int out_size, void* d_ws, size_t ws_size,
                              hipStream_t stream) {
    if (ws_size < WS_NEEDED) return;  // loud failure rather than corruption

    const int*   X     = (const int*)d_in[0];
    const float* emb   = (const float*)d_in[1];
    const float* Wih0  = (const float*)d_in[2];
    const float* Whh0  = (const float*)d_in[3];
    const float* bih0  = (const float*)d_in[4];
    const float* bhh0  = (const float*)d_in[5];
    const float* Wih1  = (const float*)d_in[6];
    const float* Whh1  = (const float*)d_in[7];
    const float* bih1  = (const float*)d_in[8];
    const float* bhh1  = (const float*)d_in[9];
    const float* Wfc   = (const float*)d_in[10];
    const float* bfc   = (const float*)d_in[11];

    char* ws = (char*)d_ws;
    _Float16* Wfc16   = (_Float16*)(ws + WS_WFC16);
    _Float16* xg      = (_Float16*)(ws + WS_XG);
    _Float16* Wih0f16 = (_Float16*)(ws + WS_WIH0);
    _Float16* Wih1f16 = (_Float16*)(ws + WS_WIH1);
    float*    xp0     = (float*)(ws + WS_XP0);
    float*    xp1     = (float*)(ws + WS_XP1);
    unsigned* h0ex    = (unsigned*)(ws + WS_H0EX);
    unsigned* h1ex    = (unsigned*)(ws + WS_H1EX);
    unsigned* flags0  = (unsigned*)(ws + WS_FLAGS);
    unsigned* flags1  = flags0 + 1024;
    unsigned* flagsS  = flags0 + 2048;

    float* logits     = (float*)d_out;                          // [16,256,32000]
    float* hidden     = (float*)d_out + (size_t)BB * TT * VV;   // [2,16,512]
    float* out2       = hidden + 2 * BB * HH;                   // [16,256,512]

    // prep
    hipLaunchKernelGGL(init_flags_k, dim3(16), dim3(256), 0, stream, flags0);
    hipLaunchKernelGGL(gather_embed_k, dim3(BB * TT), dim3(256), 0, stream, X, emb, xg);
    hipLaunchKernelGGL(cvt_f32_f16_k, dim3((HH * EE) / 256), dim3(256), 0, stream, Wih0, Wih0f16, HH * EE);
    hipLaunchKernelGGL(cvt_f32_f16_k, dim3((HH * HH) / 256), dim3(256), 0, stream, Wih1, Wih1f16, HH * HH);
    hipLaunchKernelGGL(cvt_f32_f16_k, dim3((VV * HH) / 256), dim3(256), 0, stream, Wfc, Wfc16, VV * HH);

    // layer-0 input projection -> xp0 (t-major), bias = b_ih0 + b_hh0
    hipLaunchKernelGGL((gemm_f16_k<true, false>), dim3((4096 / 128) * (HH / 128)), dim3(256), 0, stream,
                       xg, Wih0f16, bih0, bhh0, xp0, 4096, HH, EE);

    // fused flag-protocol recurrence (8 rec blocks + 64 xp1-stage blocks)
    hipLaunchKernelGGL(rnn_pipe_k, dim3(72), dim3(256), 0, stream,
                       Whh0, Whh1, Wih1f16, bih1, bhh1, xp0, xp1,
                       h0ex, h1ex, hidden, out2, flags0, flags1, flagsS);

    // final FC: logits = h1ex(APERM rows t*16+b) @ Wfc^T + b_fc
    hipLaunchKernelGGL((gemm_f16_k<false, true>), dim3((4096 / 128) * (VV / 128)), dim3(256), 0, stream,
                       (const _Float16*)h1ex, Wfc16, bfc, nullptr, logits, 4096, VV, HH);
}

// Round 8
// 2125.846 us; speedup vs baseline: 1.4546x; 1.2330x over previous
//
#include <hip/hip_runtime.h>
#include <hip/hip_fp16.h>

// Problem constants
#define BB 16
#define TT 256
#define HH 512
#define EE 256
#define VV 32000

using half8   = __attribute__((ext_vector_type(8))) _Float16;
using float4v = __attribute__((ext_vector_type(4))) float;
typedef unsigned long long u64;

// ---------------- ws layout (bytes) ----------------
#define WS_WFC16   0u                       // 32000*512*2 = 32768000
#define WS_XG      32768000u                // 4096*256*2  = 2097152
#define WS_WIH0    34865152u                // 512*256*2   = 262144
#define WS_WIH1    35127296u                // 512*512*2   = 524288
#define WS_XP0     35651584u                // 256*16*512*4= 8388608  (t-major [T][B][H], incl b_ih0+b_hh0)
#define WS_XP1     44040192u                // 8388608  (t-major [T][B][H], incl b_ih1+b_hh1)
#define WS_H0EX    52428800u                // 4194304  [T][16][256] u32 (f16 pairs)
#define WS_H1EX    56623104u                // 4194304  [T][16][256] u32 (f16 pairs; FC GEMM reads via APERM)
#define WS_FLAGS   60817408u                // 16384: flags0 2048 u32 (per-wave, [T][8]), flag1x 256 u32
#define WS_NEEDED  60833792u

// ---------------- tiny prep kernels ----------------
__global__ void init_flags_k(unsigned* f) {
    f[blockIdx.x * 256 + threadIdx.x] = 0u;   // 9*256 = 2304 >= 2048+256 used
}

__global__ void cvt_f32_f16_k(const float* __restrict__ s, _Float16* __restrict__ d, int n) {
    int i = blockIdx.x * 256 + threadIdx.x;
    if (i < n) d[i] = (_Float16)s[i];
}

__global__ void gather_embed_k(const int* __restrict__ X, const float* __restrict__ emb,
                               _Float16* __restrict__ xg) {
    int m = blockIdx.x;            // m = b*T + t
    int e = threadIdx.x;           // 256 threads
    int row = X[m];
    xg[m * EE + e] = (_Float16)emb[(size_t)row * EE + e];
}

// ---------------- generic f16 GEMM: C[M,N] = A[M,K] * B[N,K]^T + bias0 + bias1 ----------------
// PERM : store C at [t][b][n] with logical row m = b*256+t  (xp0 production)
// APERM: read A row m from physical row (m&255)*16 + (m>>8) (h1ex consumption: [t*16+b] rows)
template <bool PERM, bool APERM>
__global__ __launch_bounds__(256)
void gemm_f16_k(const _Float16* __restrict__ A, const _Float16* __restrict__ Bm,
                const float* __restrict__ bias0, const float* __restrict__ bias1,
                float* __restrict__ C, int M, int N, int K) {
    __shared__ _Float16 As[128][40];
    __shared__ _Float16 Bs[128][40];
    const int tid = threadIdx.x;
    const int l = tid & 63, w = tid >> 6;
    const int ntiles = N >> 7;
    const int m0 = (blockIdx.x / ntiles) << 7;
    const int n0 = (blockIdx.x % ntiles) << 7;
    const int wr = (w >> 1) << 6, wc = (w & 1) << 6;
    const int lrow = tid >> 1, lseg = (tid & 1) << 4;
    const int ar = l & 15, ak = (l >> 4) << 3;

    float4v acc[4][4] = {};

    const int am = m0 + lrow;
    const size_t arow = APERM ? (size_t)((am & 255) * 16 + (am >> 8)) : (size_t)am;

    for (int kt = 0; kt < K; kt += 32) {
        const _Float16* ga = A  + arow * K + kt + lseg;
        const _Float16* gb = Bm + (size_t)(n0 + lrow) * K + kt + lseg;
        *(int4*)&As[lrow][lseg]     = *(const int4*)ga;
        *(int4*)&As[lrow][lseg + 8] = *(const int4*)(ga + 8);
        *(int4*)&Bs[lrow][lseg]     = *(const int4*)gb;
        *(int4*)&Bs[lrow][lseg + 8] = *(const int4*)(gb + 8);
        __syncthreads();

        half8 af[4], bf[4];
#pragma unroll
        for (int m = 0; m < 4; ++m) af[m] = *(half8*)&As[wr + m * 16 + ar][ak];
#pragma unroll
        for (int n = 0; n < 4; ++n) bf[n] = *(half8*)&Bs[wc + n * 16 + ar][ak];
#pragma unroll
        for (int m = 0; m < 4; ++m)
#pragma unroll
            for (int n = 0; n < 4; ++n)
                acc[m][n] = __builtin_amdgcn_mfma_f32_16x16x32_f16(af[m], bf[n], acc[m][n], 0, 0, 0);
        __syncthreads();
    }

#pragma unroll
    for (int m = 0; m < 4; ++m) {
#pragma unroll
        for (int n = 0; n < 4; ++n) {
            const int col = n0 + wc + n * 16 + (l & 15);
            float bv = (bias0 ? bias0[col] : 0.f) + (bias1 ? bias1[col] : 0.f);
#pragma unroll
            for (int r = 0; r < 4; ++r) {
                const int row = m0 + wr + m * 16 + ((l >> 4) << 2) + r;
                float v = acc[m][n][r] + bv;
                if (PERM) {
                    int t = row & 255, b = row >> 8;
                    C[(size_t)((t << 4) + b) * HH + col] = v;
                } else {
                    C[(size_t)row * N + col] = v;
                }
            }
        }
    }
}

// fast tanh: 1 - 2/(e^{2x}+1)
__device__ __forceinline__ float tanh_fast(float x) {
    float e = __expf(2.0f * x);
    return 1.0f - 2.0f * __builtin_amdgcn_rcpf(e + 1.0f);
}

// ---------------- fused RNN pipeline (one block per layer: in-block recurrence) ----------------
// grid = 34 blocks x 512 threads (8 waves).
//   block 0: layer-0 recurrence. block 1: layer-1. Each block owns a WHOLE layer:
//     8 waves x 64 cols; weights per wave = 4ct x 16kt frags; kt 0..3 in LDS (128KB shared),
//     kt 4..15 in VGPRs (192/wave; 2 waves/SIMD -> 256-reg cap; demand ~245 => no spill).
//     h[t-1] -> h[t] NEVER leaves the CU (LDS hbuf + 2 barriers) — no per-step fabric trip.
//     Layer-0 has ZERO polls; per-wave deferred flags released one step late (drain free).
//   blocks 2..33: xp1 stage (t-stripe j = bi-2, handles t = j + 32*i): poll layer-0's 8
//     per-wave flags for t, read h0ex as A-fragments, xp1[t] = h0[t]@W_ih1^T + biases,
//     publish + __syncthreads (drain) + one flag1x[t]. ~40us slack per t: off critical path.
__global__ __launch_bounds__(512, 2)
void rnn_pipe_k(const float* __restrict__ Whh0, const float* __restrict__ Whh1,
                const _Float16* __restrict__ Wih1f16,
                const float* __restrict__ bih1, const float* __restrict__ bhh1,
                const float* __restrict__ xp0, float* __restrict__ xp1,
                unsigned* __restrict__ h0ex, unsigned* __restrict__ h1ex,
                float* __restrict__ out_hidden, float* __restrict__ out2f32,
                unsigned* __restrict__ flags0, unsigned* __restrict__ flag1x)
{
    __shared__ _Float16 hbuf[16][520];            // h[t-1], 16.6 KB
    __shared__ _Float16 wlds[8 * 4 * 4 * 64 * 8]; // K-tiles 0..3: [w][ct][kt][l][8], 128 KB

    const int tid = threadIdx.x;
    const int l = tid & 63, w = tid >> 6;     // 8 waves
    const int lq = l >> 4;                    // 0..3
    const int kq = lq << 3;                   // {0,8,16,24}
    const int c15 = l & 15;
    const int bi = blockIdx.x;

    if (bi < 2) {
        // ================= recurrence block (one per layer) =================
        const int layer = bi;
        const float* Whh = layer ? Whh1 : Whh0;
        unsigned* hex = layer ? h1ex : h0ex;

        int col[4];
#pragma unroll
        for (int ct = 0; ct < 4; ++ct) col[ct] = w * 64 + ct * 16 + c15;

        // --- W_hh fragments: kt 0..3 -> LDS, kt 4..15 -> 192 VGPRs ---
        half8 wf[4][12];
#pragma unroll
        for (int ct = 0; ct < 4; ++ct) {
            const float* wrow = Whh + (size_t)col[ct] * HH;
#pragma unroll
            for (int kt = 0; kt < 16; ++kt) {
                const float* s = wrow + kt * 32 + kq;
                float4v f0 = *(const float4v*)s;
                float4v f1 = *(const float4v*)(s + 4);
                half8 h;
#pragma unroll
                for (int i = 0; i < 4; ++i) { h[i] = (_Float16)f0[i]; h[i + 4] = (_Float16)f1[i]; }
                if (kt < 4) *(half8*)&wlds[((((w * 4 + ct) * 4) + kt) * 64 + l) * 8] = h;
                else wf[ct][kt - 4] = h;
            }
        }
        __syncthreads();   // wlds visible

        for (int t = 0; t < TT; ++t) {
            unsigned fpre = 1u;
            // ---- A: layer0 per-wave deferred flag for t-1 (publishes long since issued) ----
            if (layer == 0) {
                if (t > 0) {
                    asm volatile("s_waitcnt vmcnt(0)" ::: "memory");
                    if (l == 0)
                        __hip_atomic_store(&flags0[(t - 1) * 8 + w], 1u,
                                           __ATOMIC_RELEASE, __HIP_MEMORY_SCOPE_AGENT);
                }
            } else {
                // relaxed preload of this step's xp1 flag; resolves under the MFMAs below
                fpre = __hip_atomic_load(&flag1x[t], __ATOMIC_RELAXED, __HIP_MEMORY_SCOPE_AGENT);
            }

            float4v acc[4] = {};
            // ---- B1: LDS weight K-tiles 0..3 ----
            if (t > 0) {
#pragma unroll
                for (int kt = 0; kt < 4; ++kt) {
                    half8 a = *(const half8*)&hbuf[c15][kt * 32 + kq];
#pragma unroll
                    for (int ct = 0; ct < 4; ++ct) {
                        half8 b = *(const half8*)&wlds[((((w * 4 + ct) * 4) + kt) * 64 + l) * 8];
                        acc[ct] = __builtin_amdgcn_mfma_f32_16x16x32_f16(a, b, acc[ct], 0, 0, 0);
                    }
                }
                // ---- B2a: VGPR weight K-tiles 4..7 ----
#pragma unroll
                for (int kt = 4; kt < 8; ++kt) {
                    half8 a = *(const half8*)&hbuf[c15][kt * 32 + kq];
#pragma unroll
                    for (int ct = 0; ct < 4; ++ct)
                        acc[ct] = __builtin_amdgcn_mfma_f32_16x16x32_f16(a, wf[ct][kt - 4], acc[ct], 0, 0, 0);
                }
            }

            // ---- resolve layer-1 flag (fast path: local acquire fence only) ----
            if (layer == 1) {
                if (fpre) {
                    __builtin_amdgcn_fence(__ATOMIC_ACQUIRE, "agent");
                } else {
                    while (!__hip_atomic_load(&flag1x[t], __ATOMIC_ACQUIRE, __HIP_MEMORY_SCOPE_AGENT))
                        __builtin_amdgcn_s_sleep(2);
                }
            }

            // ---- X: issue xp[t] loads (latency hides under B2b MFMAs) ----
            float xv[4][4];
            if (layer == 0) {
#pragma unroll
                for (int ct = 0; ct < 4; ++ct)
#pragma unroll
                    for (int r = 0; r < 4; ++r)
                        xv[ct][r] = xp0[(size_t)(t * 16 + lq * 4 + r) * HH + col[ct]];
            } else {
#pragma unroll
                for (int ct = 0; ct < 4; ++ct)
#pragma unroll
                    for (int r = 0; r < 4; ++r)
                        xv[ct][r] = __hip_atomic_load(&xp1[(size_t)(t * 16 + lq * 4 + r) * HH + col[ct]],
                                                      __ATOMIC_RELAXED, __HIP_MEMORY_SCOPE_AGENT);
            }

            // ---- B2b: VGPR weight K-tiles 8..15 ----
            if (t > 0) {
#pragma unroll
                for (int kt = 8; kt < 16; ++kt) {
                    half8 a = *(const half8*)&hbuf[c15][kt * 32 + kq];
#pragma unroll
                    for (int ct = 0; ct < 4; ++ct)
                        acc[ct] = __builtin_amdgcn_mfma_f32_16x16x32_f16(a, wf[ct][kt - 4], acc[ct], 0, 0, 0);
                }
            }

            // ---- D: tanh + outputs + pack ----
            unsigned pk[4][4];
#pragma unroll
            for (int ct = 0; ct < 4; ++ct) {
#pragma unroll
                for (int r = 0; r < 4; ++r) {
                    const int b = lq * 4 + r;
                    float hv = tanh_fast(xv[ct][r] + acc[ct][r]);
                    if (layer == 1)
                        out2f32[((size_t)(b << 8) + t) * HH + col[ct]] = hv;
                    if (t == TT - 1)
                        out_hidden[(size_t)(layer * BB + b) * HH + col[ct]] = hv;
                    unsigned short mu = __builtin_bit_cast(unsigned short, (_Float16)hv);
                    int ov = __shfl_xor((int)mu, 1, 64);
                    pk[ct][r] = (unsigned)mu | ((unsigned)ov << 16);   // valid on even lanes
                }
            }

            // ---- E: publish h[t] (fire-and-forget relaxed agent stores) ----
            if ((l & 1) == 0) {
#pragma unroll
                for (int ct = 0; ct < 4; ++ct)
#pragma unroll
                    for (int r = 0; r < 4; ++r)
                        __hip_atomic_store(&hex[((size_t)t * 16 + lq * 4 + r) * 256 + (col[ct] >> 1)],
                                           pk[ct][r], __ATOMIC_RELAXED, __HIP_MEMORY_SCOPE_AGENT);
            }

            // ---- F: raw barrier — all waves done reading hbuf (no vmcnt drain) ----
            asm volatile("" ::: "memory");
            __builtin_amdgcn_s_barrier();
            asm volatile("" ::: "memory");

            // ---- G: write h[t] into hbuf; LDS fence + barrier ----
            if ((l & 1) == 0) {
#pragma unroll
                for (int ct = 0; ct < 4; ++ct)
#pragma unroll
                    for (int r = 0; r < 4; ++r)
                        *(unsigned*)&hbuf[lq * 4 + r][col[ct]] = pk[ct][r];
            }
            asm volatile("s_waitcnt lgkmcnt(0)" ::: "memory");
            __builtin_amdgcn_s_barrier();
            asm volatile("" ::: "memory");
        }

        if (layer == 0) {
            asm volatile("s_waitcnt vmcnt(0)" ::: "memory");
            if (l == 0)
                __hip_atomic_store(&flags0[(TT - 1) * 8 + w], 1u,
                                   __ATOMIC_RELEASE, __HIP_MEMORY_SCOPE_AGENT);
        }
    } else {
        // ================= xp1 stage: t-striped feed-forward GEMM =================
        const int stripe = bi - 2;               // 0..31, handles t = stripe + 32i
        float bsum[4];
        int col[4];
#pragma unroll
        for (int ct = 0; ct < 4; ++ct) {
            col[ct] = w * 64 + ct * 16 + c15;
            bsum[ct] = bih1[col[ct]] + bhh1[col[ct]];
        }
        const u64* hx = (const u64*)h0ex;

        for (int i = 0; i < 8; ++i) {
            const int t = stripe + 32 * i;
            // poll all 8 layer-0 per-wave flags for step t
            if (w == 0) {
                for (;;) {
                    unsigned v = 1u;
                    if (l < 8)
                        v = __hip_atomic_load(&flags0[t * 8 + l],
                                              __ATOMIC_ACQUIRE, __HIP_MEMORY_SCOPE_AGENT);
                    if (__all(v != 0)) break;
                    __builtin_amdgcn_s_sleep(32);
                }
            }
            __syncthreads();

            // h0[t] A-fragments direct from exchange (relaxed agent u64 loads)
            half8 af[16];
            const size_t rb = ((size_t)t * 16 + c15) * 128 + (kq >> 2);
#pragma unroll
            for (int kt = 0; kt < 16; ++kt) {
                u64 d0 = __hip_atomic_load(hx + rb + kt * 8,     __ATOMIC_RELAXED, __HIP_MEMORY_SCOPE_AGENT);
                u64 d1 = __hip_atomic_load(hx + rb + kt * 8 + 1, __ATOMIC_RELAXED, __HIP_MEMORY_SCOPE_AGENT);
                union { u64 u[2]; half8 h; } cv;
                cv.u[0] = d0; cv.u[1] = d1;
                af[kt] = cv.h;
            }
            float4v acc[4];
#pragma unroll
            for (int ct = 0; ct < 4; ++ct) {
                acc[ct][0] = bsum[ct]; acc[ct][1] = bsum[ct];
                acc[ct][2] = bsum[ct]; acc[ct][3] = bsum[ct];
            }
#pragma unroll
            for (int ct = 0; ct < 4; ++ct) {
                const _Float16* wp = Wih1f16 + (size_t)col[ct] * HH + kq;
#pragma unroll
                for (int kt = 0; kt < 16; ++kt) {
                    half8 bf = *(const half8*)(wp + kt * 32);
                    acc[ct] = __builtin_amdgcn_mfma_f32_16x16x32_f16(af[kt], bf, acc[ct], 0, 0, 0);
                }
            }
            // publish xp1[t] (agent scope), then one flag for the whole t
#pragma unroll
            for (int ct = 0; ct < 4; ++ct)
#pragma unroll
                for (int r = 0; r < 4; ++r)
                    __hip_atomic_store(&xp1[(size_t)(t * 16 + lq * 4 + r) * HH + col[ct]], acc[ct][r],
                                       __ATOMIC_RELAXED, __HIP_MEMORY_SCOPE_AGENT);
            __syncthreads();   // implicit per-wave vmcnt(0) before barrier -> stores drained
            if (tid == 0)
                __hip_atomic_store(&flag1x[t], 1u, __ATOMIC_RELEASE, __HIP_MEMORY_SCOPE_AGENT);
        }
    }
}

// ---------------- launch ----------------
extern "C" void kernel_launch(void* const* d_in, const int* in_sizes, int n_in,
                              void* d_out, int out_size, void* d_ws, size_t ws_size,
                              hipStream_t stream) {
    if (ws_size < WS_NEEDED) return;  // loud failure rather than corruption

    const int*   X     = (const int*)d_in[0];
    const float* emb   = (const float*)d_in[1];
    const float* Wih0  = (const float*)d_in[2];
    const float* Whh0  = (const float*)d_in[3];
    const float* bih0  = (const float*)d_in[4];
    const float* bhh0  = (const float*)d_in[5];
    const float* Wih1  = (const float*)d_in[6];
    const float* Whh1  = (const float*)d_in[7];
    const float* bih1  = (const float*)d_in[8];
    const float* bhh1  = (const float*)d_in[9];
    const float* Wfc   = (const float*)d_in[10];
    const float* bfc   = (const float*)d_in[11];

    char* ws = (char*)d_ws;
    _Float16* Wfc16   = (_Float16*)(ws + WS_WFC16);
    _Float16* xg      = (_Float16*)(ws + WS_XG);
    _Float16* Wih0f16 = (_Float16*)(ws + WS_WIH0);
    _Float16* Wih1f16 = (_Float16*)(ws + WS_WIH1);
    float*    xp0     = (float*)(ws + WS_XP0);
    float*    xp1     = (float*)(ws + WS_XP1);
    unsigned* h0ex    = (unsigned*)(ws + WS_H0EX);
    unsigned* h1ex    = (unsigned*)(ws + WS_H1EX);
    unsigned* flags0  = (unsigned*)(ws + WS_FLAGS);
    unsigned* flag1x  = flags0 + TT * 8;

    float* logits     = (float*)d_out;                          // [16,256,32000]
    float* hidden     = (float*)d_out + (size_t)BB * TT * VV;   // [2,16,512]
    float* out2       = hidden + 2 * BB * HH;                   // [16,256,512]

    // prep
    hipLaunchKernelGGL(init_flags_k, dim3(9), dim3(256), 0, stream, flags0);
    hipLaunchKernelGGL(gather_embed_k, dim3(BB * TT), dim3(256), 0, stream, X, emb, xg);
    hipLaunchKernelGGL(cvt_f32_f16_k, dim3((HH * EE) / 256), dim3(256), 0, stream, Wih0, Wih0f16, HH * EE);
    hipLaunchKernelGGL(cvt_f32_f16_k, dim3((HH * HH) / 256), dim3(256), 0, stream, Wih1, Wih1f16, HH * HH);
    hipLaunchKernelGGL(cvt_f32_f16_k, dim3((VV * HH) / 256), dim3(256), 0, stream, Wfc, Wfc16, VV * HH);

    // layer-0 input projection -> xp0 (t-major), bias = b_ih0 + b_hh0
    hipLaunchKernelGGL((gemm_f16_k<true, false>), dim3((4096 / 128) * (HH / 128)), dim3(256), 0, stream,
                       xg, Wih0f16, bih0, bhh0, xp0, 4096, HH, EE);

    // fused recurrence: 2 whole-layer blocks (in-block h chain) + 32 xp1-stage blocks
    hipLaunchKernelGGL(rnn_pipe_k, dim3(34), dim3(512), 0, stream,
                       Whh0, Whh1, Wih1f16, bih1, bhh1, xp0, xp1,
                       h0ex, h1ex, hidden, out2, flags0, flag1x);

    // final FC: logits = h1ex(APERM rows t*16+b) @ Wfc^T + b_fc
    hipLaunchKernelGGL((gemm_f16_k<false, true>), dim3((4096 / 128) * (VV / 128)), dim3(256), 0, stream,
                       (const _Float16*)h1ex, Wfc16, bfc, nullptr, logits, 4096, VV, HH);
}